// Round 1
// baseline (253.369 us; speedup 1.0000x reference)
//
#include <hip/hip_runtime.h>

#define Bn 8
#define Nn 4096
#define Pn 4096
#define Kn 32
#define Cn 128

using float4v = __attribute__((ext_vector_type(4))) float;
using short8  = __attribute__((ext_vector_type(8))) short;

__device__ __forceinline__ unsigned short bf16b(float f) {
  union { float f; unsigned u; } v; v.f = f;
  unsigned r = v.u + 0x7FFFu + ((v.u >> 16) & 1u);   // round-nearest-even
  return (unsigned short)(r >> 16);
}

// (hi16(x)) | (hi16(y)<<16) — truncating f32->bf16 pair pack, one v_perm_b32
__device__ __forceinline__ unsigned pkhi(float x, float y) {
  return __builtin_amdgcn_perm(__float_as_uint(y), __float_as_uint(x), 0x07060302u);
}

// ---------------------------------------------------------------------------
// prep: blocks 0-15: WlT[n][k] = bf16(Wl[k][n]); blocks 16-47: xyz copy into
// d_out (+ block 16 zeroes gacc). Folds 2 extra dispatches away.
// ---------------------------------------------------------------------------
__global__ __launch_bounds__(256) void prep(const float* __restrict__ Wl,
                                            unsigned short* __restrict__ WlT,
                                            const float* __restrict__ xyz,
                                            float* __restrict__ out,
                                            float* __restrict__ gacc) {
  __shared__ unsigned short tile[128 * 130];
  const int t = threadIdx.x, blk = blockIdx.x;
  if (blk < 16) {
#pragma unroll
    for (int i = 0; i < 64; ++i) {
      int idx = i * 256 + t;
      int kl = idx >> 7, n = idx & 127;
      tile[n * 130 + kl] = bf16b(Wl[(size_t)(blk * 128 + kl) * 128 + n]);
    }
    __syncthreads();
#pragma unroll
    for (int i = 0; i < 64; ++i) {
      int idx = i * 256 + t;
      int n = idx >> 7, kl = idx & 127;
      WlT[(size_t)n * 2048 + blk * 128 + kl] = tile[n * 130 + kl];
    }
  } else {
    if (blk == 16) gacc[t] = 0.f;
    const int i0 = (blk - 16) * 3072 + t * 12;   // 32 blocks x 3072 f32 = 98304
#pragma unroll
    for (int i = 0; i < 3; ++i)
      *(float4v*)(out + i0 + i * 4) = *(const float4v*)(xyz + i0 + i * 4);
  }
}

// ---------------------------------------------------------------------------
// stage1: LDS-free. B-fragments gathered directly to registers: lane reads
// data[nk[q*8+j]][ct*16+l15] as scalar dwords (each wave-instr = 4 fully
// consumed 64B lines). 8 per-lane neighbor ids via broadcast int4 loads.
// 256-thread blocks (4 waves x 4 points), no barriers, occupancy VGPR-bound.
// ---------------------------------------------------------------------------
__global__ __launch_bounds__(256, 3) void stage1(
    const float* __restrict__ points, const float* __restrict__ lc,
    const int* __restrict__ nl, const int* __restrict__ didx,
    const float* __restrict__ Ww, const float* __restrict__ bwv,
    unsigned short* __restrict__ Mglob) {
  const int t = threadIdx.x;
  const int lane = t & 63, wv = t >> 6;
  const int l15 = lane & 15, q = lane >> 4;
  const int b = blockIdx.x & 7;               // XCD-affine batch
  const int pg = blockIdx.x >> 3;             // 0..255, 16 points/block
  const int db = didx[b];
  const char* __restrict__ pbase = (const char*)(points + (size_t)db * Nn * Cn);
  const float Ww0 = Ww[l15], Ww1 = Ww[16 + l15], Ww2 = Ww[32 + l15];
  const float bw0 = bwv[l15];

  const int p0 = pg * 16 + wv * 4;
#pragma unroll 1
  for (int pi = 0; pi < 4; ++pi) {
    const int p = p0 + pi;
    const unsigned pk = (unsigned)((db * Pn + p) * Kn);

    // this lane's 8 neighbor ids: nk[j] = nl[pk + q*8 + j] (broadcast loads)
    int nk[8];
    const int4* __restrict__ nlq = (const int4*)(nl + pk + q * 8);
    *(int4*)&nk[0] = nlq[0];
    *(int4*)&nk[4] = nlq[1];

    // weight A-frag: A[m=w=l15][k=q*8+j]  (RNE — cheap, 8 values)
    const float* __restrict__ lcp = lc + (size_t)(pk + q * 8) * 3;
    float la[24];
#pragma unroll
    for (int v = 0; v < 6; ++v) *(float4v*)&la[v * 4] = *(const float4v*)(lcp + v * 4);
    short8 af;
#pragma unroll
    for (int j = 0; j < 8; ++j) {
      float w = bw0 + la[3 * j] * Ww0 + la[3 * j + 1] * Ww1 + la[3 * j + 2] * Ww2;
      af[j] = (short)bf16b(w);
    }

    // per-lane gather bases (32-bit voffset, SADDR form): row nk[j], col l15
    unsigned base[8];
#pragma unroll
    for (int j = 0; j < 8; ++j)
      base[j] = ((unsigned)nk[j] << 9) + (unsigned)(l15 * 4);

    // gather all 64 floats: f[ct*8+j] = data[k=q*8+j][c=ct*16+l15]
    float f[64];
#pragma unroll
    for (int ct = 0; ct < 8; ++ct)
#pragma unroll
      for (int j = 0; j < 8; ++j)
        f[ct * 8 + j] = *(const float*)(pbase + base[j] + ct * 64);

    const unsigned moff = ((unsigned)(b * Pn + p)) << 11;
#pragma unroll
    for (int ct = 0; ct < 8; ++ct) {
      union { short8 s; unsigned u[4]; } bv;
#pragma unroll
      for (int i = 0; i < 4; ++i)
        bv.u[i] = pkhi(f[ct * 8 + 2 * i], f[ct * 8 + 2 * i + 1]);
      float4v d = {0.f, 0.f, 0.f, 0.f};
      d = __builtin_amdgcn_mfma_f32_16x16x32_bf16(af, bv.s, d, 0, 0, 0);
      uint2 u;
      u.x = pkhi(d[0], d[1]);
      u.y = pkhi(d[2], d[3]);
      *(uint2*)&Mglob[moff + (ct * 16 + l15) * 16 + q * 4] = u;
    }
  }
}

// ---------------------------------------------------------------------------
// stage2: Y(32768x128) = M(32768x2048) @ Wl(2048x128), LDS-free streaming.
// 512 blocks x 64 rows; fragments loaded straight from global (M rows and
// WlT rows are frag-layout: dwordx4/lane covers 16 full 64B lines). 2-deep
// register double-buffer -> compiler emits counted vmcnt, no barrier drain.
// ---------------------------------------------------------------------------
__global__ __launch_bounds__(256) void stage2(
    const unsigned short* __restrict__ Mglob,
    const unsigned short* __restrict__ WlT, const float* __restrict__ blv,
    float* __restrict__ xout, float* __restrict__ gacc) {
  __shared__ float red[256];
  const int t = threadIdx.x, lane = t & 63, wave = t >> 6;
  const int l15 = lane & 15, q = lane >> 4;
  const int bidx = blockIdx.x & 7;                 // XCD-affine batch
  const int pt0 = (blockIdx.x >> 3) * 64;
  const size_t row0 = (size_t)bidx * Pn + pt0;

  const unsigned short* __restrict__ ap = Mglob + (row0 + l15) * 2048 + q * 8;
  const unsigned short* __restrict__ bp =
      WlT + (size_t)(wave * 32 + l15) * 2048 + q * 8;

  float4v acc[4][2];
#pragma unroll
  for (int rt = 0; rt < 4; ++rt)
#pragma unroll
    for (int nt = 0; nt < 2; ++nt) acc[rt][nt] = (float4v){0.f, 0.f, 0.f, 0.f};

  short8 aA[4], bA[2], aB[4], bB[2];

#define LDA(buf, kk)                                              \
  buf[0] = *(const short8*)(ap + (kk) * 32);                      \
  buf[1] = *(const short8*)(ap + 32768 + (kk) * 32);              \
  buf[2] = *(const short8*)(ap + 65536 + (kk) * 32);              \
  buf[3] = *(const short8*)(ap + 98304 + (kk) * 32);
#define LDB(buf, kk)                                              \
  buf[0] = *(const short8*)(bp + (kk) * 32);                      \
  buf[1] = *(const short8*)(bp + 32768 + (kk) * 32);
#define CMP(ab, bb)                                                                  \
  acc[0][0] = __builtin_amdgcn_mfma_f32_16x16x32_bf16(ab[0], bb[0], acc[0][0], 0, 0, 0); \
  acc[0][1] = __builtin_amdgcn_mfma_f32_16x16x32_bf16(ab[0], bb[1], acc[0][1], 0, 0, 0); \
  acc[1][0] = __builtin_amdgcn_mfma_f32_16x16x32_bf16(ab[1], bb[0], acc[1][0], 0, 0, 0); \
  acc[1][1] = __builtin_amdgcn_mfma_f32_16x16x32_bf16(ab[1], bb[1], acc[1][1], 0, 0, 0); \
  acc[2][0] = __builtin_amdgcn_mfma_f32_16x16x32_bf16(ab[2], bb[0], acc[2][0], 0, 0, 0); \
  acc[2][1] = __builtin_amdgcn_mfma_f32_16x16x32_bf16(ab[2], bb[1], acc[2][1], 0, 0, 0); \
  acc[3][0] = __builtin_amdgcn_mfma_f32_16x16x32_bf16(ab[3], bb[0], acc[3][0], 0, 0, 0); \
  acc[3][1] = __builtin_amdgcn_mfma_f32_16x16x32_bf16(ab[3], bb[1], acc[3][1], 0, 0, 0);

  LDA(aA, 0) LDB(bA, 0)
#pragma unroll 1
  for (int kk = 0; kk < 62; kk += 2) {
    LDA(aB, kk + 1) LDB(bB, kk + 1)
    CMP(aA, bA)
    LDA(aA, kk + 2) LDB(bA, kk + 2)
    CMP(aB, bB)
  }
  LDA(aB, 63) LDB(bB, 63)
  CMP(aA, bA)
  CMP(aB, bB)
#undef LDA
#undef LDB
#undef CMP

  // epilogue: bias, transposed store (B,C,P), disjoint per-wave channel stats
#pragma unroll
  for (int nt = 0; nt < 2; ++nt) {
    const int ch = wave * 32 + nt * 16 + l15;
    const float bb = blv[ch];
    float s = 0.f, sq = 0.f;
#pragma unroll
    for (int rt = 0; rt < 4; ++rt) {
      float4v o;
#pragma unroll
      for (int r = 0; r < 4; ++r) {
        float v = acc[rt][nt][r] + bb; o[r] = v; s += v; sq += v * v;
      }
      *(float4v*)(xout + ((size_t)bidx * Cn + ch) * Pn + pt0 + rt * 16 + q * 4) = o;
    }
    s += __shfl_xor(s, 16); s += __shfl_xor(s, 32);
    sq += __shfl_xor(sq, 16); sq += __shfl_xor(sq, 32);
    if (lane < 16) { red[ch] = s; red[128 + ch] = sq; }
  }
  __syncthreads();
  atomicAdd(&gacc[t], red[t]);
}

// ---------------------------------------------------------------------------
// finalize: layernorm (per-channel over B*P) + relu, in place on x chunk
// ---------------------------------------------------------------------------
__global__ __launch_bounds__(256) void finalize_ln(float* __restrict__ x,
                                                   const float* __restrict__ gacc,
                                                   const float* __restrict__ gamma,
                                                   const float* __restrict__ beta) {
  const int idx = blockIdx.x * 256 + threadIdx.x;
  const int fi = idx * 4;
  const int c = (fi >> 12) & 127;
  const float inv = 1.f / 32768.f;
  const float mean = gacc[c] * inv;
  const float var = gacc[128 + c] * inv - mean * mean;
  const float scale = rsqrtf(var + 1e-5f) * gamma[c];
  const float shift = beta[c] - mean * scale;
  float4v v = *(float4v*)(x + fi);
#pragma unroll
  for (int r = 0; r < 4; ++r) v[r] = fmaxf(v[r] * scale + shift, 0.f);
  *(float4v*)(x + fi) = v;
}

extern "C" void kernel_launch(void* const* d_in, const int* in_sizes, int n_in,
                              void* d_out, int out_size, void* d_ws, size_t ws_size,
                              hipStream_t stream) {
  const float* xyz    = (const float*)d_in[0];
  const float* points = (const float*)d_in[1];
  const float* lc     = (const float*)d_in[2];
  const int*   nl     = (const int*)d_in[3];
  const int*   didx   = (const int*)d_in[4];
  const float* Ww     = (const float*)d_in[5];
  const float* bw     = (const float*)d_in[6];
  const float* Wl     = (const float*)d_in[7];
  const float* bl     = (const float*)d_in[8];
  const float* gamma  = (const float*)d_in[9];
  const float* beta   = (const float*)d_in[10];

  float* out  = (float*)d_out;
  float* xout = out + (size_t)Bn * Pn * 3;                       // x chunk (B,C,P)
  unsigned short* WlT = (unsigned short*)d_ws;                   // 512 KB
  float* gacc = (float*)((char*)d_ws + (size_t)512 * 1024);      // 1 KB
  unsigned short* Mglob =
      (unsigned short*)((char*)d_ws + (size_t)1024 * 1024);      // 128 MB

  prep<<<48, 256, 0, stream>>>(Wl, WlT, xyz, out, gacc);
  stage1<<<2048, 256, 0, stream>>>(points, lc, nl, didx, Ww, bw, Mglob);
  stage2<<<512, 256, 0, stream>>>(Mglob, WlT, bl, xout, gacc);
  finalize_ln<<<4096, 256, 0, stream>>>(xout, gacc, gamma, beta);
}

// Round 2
// 208.135 us; speedup vs baseline: 1.2173x; 1.2173x over previous
//
#include <hip/hip_runtime.h>

#define Bn 8
#define Nn 4096
#define Pn 4096
#define Kn 32
#define Cn 128

using float4v = __attribute__((ext_vector_type(4))) float;
using short8  = __attribute__((ext_vector_type(8))) short;

__device__ __forceinline__ unsigned short bf16b(float f) {
  union { float f; unsigned u; } v; v.f = f;
  unsigned r = v.u + 0x7FFFu + ((v.u >> 16) & 1u);   // round-nearest-even
  return (unsigned short)(r >> 16);
}

// (hi16(x)) | (hi16(y)<<16) — truncating f32->bf16 pair pack, one v_perm_b32
__device__ __forceinline__ unsigned pkhi(float x, float y) {
  return __builtin_amdgcn_perm(__float_as_uint(y), __float_as_uint(x), 0x07060302u);
}

// ---------------------------------------------------------------------------
// prep: blocks 0-15: WlT[n][k] = bf16(Wl[k][n]); blocks 16-47: xyz copy into
// d_out (+ block 16 zeroes gacc). Folds 2 extra dispatches away.
// ---------------------------------------------------------------------------
__global__ __launch_bounds__(256) void prep(const float* __restrict__ Wl,
                                            unsigned short* __restrict__ WlT,
                                            const float* __restrict__ xyz,
                                            float* __restrict__ out,
                                            float* __restrict__ gacc) {
  __shared__ unsigned short tile[128 * 130];
  const int t = threadIdx.x, blk = blockIdx.x;
  if (blk < 16) {
#pragma unroll
    for (int i = 0; i < 64; ++i) {
      int idx = i * 256 + t;
      int kl = idx >> 7, n = idx & 127;
      tile[n * 130 + kl] = bf16b(Wl[(size_t)(blk * 128 + kl) * 128 + n]);
    }
    __syncthreads();
#pragma unroll
    for (int i = 0; i < 64; ++i) {
      int idx = i * 256 + t;
      int n = idx >> 7, kl = idx & 127;
      WlT[(size_t)n * 2048 + blk * 128 + kl] = tile[n * 130 + kl];
    }
  } else {
    if (blk == 16) gacc[t] = 0.f;
    const int i0 = (blk - 16) * 3072 + t * 12;   // 32 blocks x 3072 f32 = 98304
#pragma unroll
    for (int i = 0; i < 3; ++i)
      *(float4v*)(out + i0 + i * 4) = *(const float4v*)(xyz + i0 + i * 4);
  }
}

// ---------------------------------------------------------------------------
// fused: stage1+stage2 without materializing M (kills the 268 MB HBM
// round-trip). 1024 blocks x 4 waves x 32 points. Per ko-chunk ct (256 of
// 2048): each wave computes M tiles for 8 points (register gather + MFMA,
// round-1-verified path) into XOR-swizzled Mlds[32][256]; barrier; all waves
// read A-frags (point across lanes) from Mlds and B-frags for their
// 32-channel n-slice from L2-resident WlT; 32 MFMAs into f32 acc. ko
// accumulation order identical to the two-stage version -> same numerics.
// ---------------------------------------------------------------------------
__global__ __launch_bounds__(256, 4) void fused(
    const float* __restrict__ points, const float* __restrict__ lc,
    const int* __restrict__ nl, const int* __restrict__ didx,
    const float* __restrict__ Ww, const float* __restrict__ bwv,
    const unsigned short* __restrict__ WlT, const float* __restrict__ blv,
    float* __restrict__ xout, float* __restrict__ gacc) {
  __shared__ unsigned short Mlds[32 * 256];   // 16 KB, row-XOR-swizzled
  __shared__ int nlds[32 * 32];               // 4 KB
  __shared__ float red[256];

  const int t = threadIdx.x, lane = t & 63, w = t >> 6;
  const int l15 = lane & 15, q = lane >> 4;
  const int b = blockIdx.x & 7;               // XCD-affine batch
  const int pg = blockIdx.x >> 3;             // 0..127
  const int p0 = pg * 32;
  const int db = didx[b];
  const char* __restrict__ pbase = (const char*)(points + (size_t)db * Nn * Cn);

  // stage neighbor ids for the block's 32 points (4 KB)
  const int* __restrict__ nlsrc = nl + (size_t)(db * Pn + p0) * Kn;
  *(int4*)&nlds[t * 4] = *(const int4*)(nlsrc + t * 4);

  const float Ww0 = Ww[l15], Ww1 = Ww[16 + l15], Ww2 = Ww[32 + l15];
  const float bw0 = bwv[l15];

  // weight A-frags for my 8 points: A[m=w_out=l15][k=q*8+j]
  short8 af[8];
#pragma unroll
  for (int i = 0; i < 8; ++i) {
    const int p = p0 + w * 8 + i;
    const int pk = (db * Pn + p) * Kn;
    const float* __restrict__ lcp = lc + (size_t)(pk + q * 8) * 3;
    float la[24];
#pragma unroll
    for (int v = 0; v < 6; ++v) *(float4v*)&la[v * 4] = *(const float4v*)(lcp + v * 4);
#pragma unroll
    for (int j = 0; j < 8; ++j) {
      float ww = bw0 + la[3 * j] * Ww0 + la[3 * j + 1] * Ww1 + la[3 * j + 2] * Ww2;
      af[i][j] = (short)bf16b(ww);
    }
  }

  float4v acc[2][2];
#pragma unroll
  for (int pt = 0; pt < 2; ++pt)
#pragma unroll
    for (int nt = 0; nt < 2; ++nt) acc[pt][nt] = (float4v){0.f, 0.f, 0.f, 0.f};

  __syncthreads();   // nlds ready

  // my n-slice: channels w*32 .. w*32+31
  const unsigned short* __restrict__ bpt =
      WlT + (size_t)(w * 32 + l15) * 2048 + q * 8;

  for (int ct = 0; ct < 8; ++ct) {
    // ---- step1: M tiles for my 8 points, c-range [ct*16, ct*16+16)
#pragma unroll
    for (int i = 0; i < 8; ++i) {
      const int pi = w * 8 + i;
      int nk[8];
      *(int4*)&nk[0] = *(const int4*)&nlds[pi * 32 + q * 8];
      *(int4*)&nk[4] = *(const int4*)&nlds[pi * 32 + q * 8 + 4];
      float f[8];
#pragma unroll
      for (int j = 0; j < 8; ++j)
        f[j] = *(const float*)(pbase +
                 (((unsigned)nk[j] << 9) + (unsigned)(l15 * 4 + ct * 64)));
      union { short8 s; unsigned u[4]; } bv;
#pragma unroll
      for (int i2 = 0; i2 < 4; ++i2) bv.u[i2] = pkhi(f[2 * i2], f[2 * i2 + 1]);
      float4v d = {0.f, 0.f, 0.f, 0.f};
      d = __builtin_amdgcn_mfma_f32_16x16x32_bf16(af[i], bv.s, d, 0, 0, 0);
      // lane holds M[pi][koc = l15*16 + q*4 + r], r=0..3 -> pack 2 dwords
      const unsigned off =
          (unsigned)(pi * 512 + ((l15 * 32 + q * 8) ^ ((pi & 7) << 4)));
      uint2 u;
      u.x = pkhi(d[0], d[1]);
      u.y = pkhi(d[2], d[3]);
      *(uint2*)((char*)Mlds + off) = u;
    }
    __syncthreads();
    // ---- step2: Y += Mchunk @ WlT-chunk for my 32 channels
    const unsigned short* __restrict__ bp = bpt + ct * 256;
#pragma unroll
    for (int ks = 0; ks < 8; ++ks) {
      const unsigned ax = (unsigned)(ks * 64 + q * 16) ^ ((l15 & 7) << 4);
      short8 a0 = *(const short8*)((const char*)Mlds + l15 * 512 + ax);
      short8 a1 = *(const short8*)((const char*)Mlds + (16 + l15) * 512 + ax);
      short8 b0 = *(const short8*)(bp + ks * 32);
      short8 b1 = *(const short8*)(bp + 32768 + ks * 32);
      acc[0][0] = __builtin_amdgcn_mfma_f32_16x16x32_bf16(a0, b0, acc[0][0], 0, 0, 0);
      acc[0][1] = __builtin_amdgcn_mfma_f32_16x16x32_bf16(a0, b1, acc[0][1], 0, 0, 0);
      acc[1][0] = __builtin_amdgcn_mfma_f32_16x16x32_bf16(a1, b0, acc[1][0], 0, 0, 0);
      acc[1][1] = __builtin_amdgcn_mfma_f32_16x16x32_bf16(a1, b1, acc[1][1], 0, 0, 0);
    }
    __syncthreads();
  }

  // epilogue: bias, transposed store (B,C,P), disjoint per-wave channel stats
#pragma unroll
  for (int nt = 0; nt < 2; ++nt) {
    const int ch = w * 32 + nt * 16 + l15;
    const float bb = blv[ch];
    float s = 0.f, sq = 0.f;
#pragma unroll
    for (int pt = 0; pt < 2; ++pt) {
      float4v o;
#pragma unroll
      for (int r = 0; r < 4; ++r) {
        float v = acc[pt][nt][r] + bb; o[r] = v; s += v; sq += v * v;
      }
      *(float4v*)(xout + ((size_t)(b * Cn + ch)) * Pn + p0 + pt * 16 + q * 4) = o;
    }
    s += __shfl_xor(s, 16); s += __shfl_xor(s, 32);
    sq += __shfl_xor(sq, 16); sq += __shfl_xor(sq, 32);
    if (lane < 16) { red[ch] = s; red[128 + ch] = sq; }
  }
  __syncthreads();
  atomicAdd(&gacc[t], red[t]);
}

// ---------------------------------------------------------------------------
// finalize: layernorm (per-channel over B*P) + relu, in place on x chunk
// ---------------------------------------------------------------------------
__global__ __launch_bounds__(256) void finalize_ln(float* __restrict__ x,
                                                   const float* __restrict__ gacc,
                                                   const float* __restrict__ gamma,
                                                   const float* __restrict__ beta) {
  const int idx = blockIdx.x * 256 + threadIdx.x;
  const int fi = idx * 4;
  const int c = (fi >> 12) & 127;
  const float inv = 1.f / 32768.f;
  const float mean = gacc[c] * inv;
  const float var = gacc[128 + c] * inv - mean * mean;
  const float scale = rsqrtf(var + 1e-5f) * gamma[c];
  const float shift = beta[c] - mean * scale;
  float4v v = *(float4v*)(x + fi);
#pragma unroll
  for (int r = 0; r < 4; ++r) v[r] = fmaxf(v[r] * scale + shift, 0.f);
  *(float4v*)(x + fi) = v;
}

extern "C" void kernel_launch(void* const* d_in, const int* in_sizes, int n_in,
                              void* d_out, int out_size, void* d_ws, size_t ws_size,
                              hipStream_t stream) {
  const float* xyz    = (const float*)d_in[0];
  const float* points = (const float*)d_in[1];
  const float* lc     = (const float*)d_in[2];
  const int*   nl     = (const int*)d_in[3];
  const int*   didx   = (const int*)d_in[4];
  const float* Ww     = (const float*)d_in[5];
  const float* bw     = (const float*)d_in[6];
  const float* Wl     = (const float*)d_in[7];
  const float* bl     = (const float*)d_in[8];
  const float* gamma  = (const float*)d_in[9];
  const float* beta   = (const float*)d_in[10];

  float* out  = (float*)d_out;
  float* xout = out + (size_t)Bn * Pn * 3;                       // x chunk (B,C,P)
  unsigned short* WlT = (unsigned short*)d_ws;                   // 512 KB
  float* gacc = (float*)((char*)d_ws + (size_t)512 * 1024);      // 1 KB

  prep<<<48, 256, 0, stream>>>(Wl, WlT, xyz, out, gacc);
  fused<<<1024, 256, 0, stream>>>(points, lc, nl, didx, Ww, bw, WlT, bl,
                                  xout, gacc);
  finalize_ln<<<4096, 256, 0, stream>>>(xout, gacc, gamma, beta);
}